// Round 6
// baseline (160.285 us; speedup 1.0000x reference)
//
#include <hip/hip_runtime.h>

#define DIM 768
#define HEADS 12
#define HDIM 64
#define BATCH 4
#define SEQ 2048
#define QSCALE 0.1803368787f   // 0.125 * log2(e) -> softmax in exp2 domain
#define MFIX 16.0f             // fixed softmax max bound (exp2 domain)
#define KVB 32                 // kv tile per group
#define QKVSZ ((size_t)BATCH * HEADS * SEQ * HDIM)

typedef __bf16 bf16x8 __attribute__((ext_vector_type(8)));
typedef float  f32x4  __attribute__((ext_vector_type(4)));
typedef float  f32x16 __attribute__((ext_vector_type(16)));
typedef unsigned short u16x8 __attribute__((ext_vector_type(8)));
typedef unsigned short ushort_t;

__device__ inline unsigned short f2bf(float x){
    unsigned int u = __float_as_uint(x);
    u += 0x7fffu + ((u >> 16) & 1u);
    return (unsigned short)(u >> 16);
}
__device__ inline unsigned int cvtpk(float lo, float hi){
    unsigned int r;
    asm("v_cvt_pk_bf16_f32 %0, %1, %2" : "=v"(r) : "v"(lo), "v"(hi));
    return r;
}
__device__ inline void gload_lds16(const void* g, void* lds) {
    __builtin_amdgcn_global_load_lds(
        (const __attribute__((address_space(1))) void*)g,
        (__attribute__((address_space(3))) void*)lds, 16, 0, 0);
}

// ---------------------------------------------------------------------------
// fp32 -> bf16 conversion for x, qkv_w, proj_w (8 elems/thread)
// ---------------------------------------------------------------------------
__global__ __launch_bounds__(256) void cvt3(
    const float* __restrict__ s0, ushort_t* __restrict__ d0, int v0,
    const float* __restrict__ s1, ushort_t* __restrict__ d1, int v1,
    const float* __restrict__ s2, ushort_t* __restrict__ d2, int v2)
{
    int idx = blockIdx.x * 256 + threadIdx.x;
    const float* s; ushort_t* d;
    if (idx < v0)           { s = s0; d = d0; }
    else if (idx < v0 + v1) { idx -= v0; s = s1; d = d1; }
    else                    { idx -= v0 + v1; s = s2; d = d2; }
    float4 a = *(const float4*)(s + (size_t)idx * 8);
    float4 b = *(const float4*)(s + (size_t)idx * 8 + 4);
    u16x8 p;
    p[0] = f2bf(a.x); p[1] = f2bf(a.y); p[2] = f2bf(a.z); p[3] = f2bf(a.w);
    p[4] = f2bf(b.x); p[5] = f2bf(b.y); p[6] = f2bf(b.z); p[7] = f2bf(b.w);
    *(u16x8*)(d + (size_t)idx * 8) = p;
}

// ---------------------------------------------------------------------------
// bf16 MFMA GEMM: C[M,N] = A[M,K] @ W[N,K]^T + bias[N]
// MODE 0: fp32 store. MODE 1: bf16 scatter -> Q[bh][n][d] (scaled), K[bh][n][d],
//         V^T[bh][d][SEQ] (packed ushort4 along seq).
// ---------------------------------------------------------------------------
template <int MODE>
__global__ __launch_bounds__(256) void gemm_mfma(
    const ushort_t* __restrict__ A, const ushort_t* __restrict__ W,
    const float* __restrict__ bias, void* __restrict__ outp,
    int M, int N, int K)
{
    __shared__ ushort_t As[128 * 64];
    __shared__ ushort_t Bs[128 * 64];

    const int tid  = threadIdx.x;
    const int lane = tid & 63;
    const int w    = tid >> 6;
    const int l16  = lane & 15;
    const int lg   = lane >> 4;
    const int wm = w >> 1, wn = w & 1;
    const int m0 = blockIdx.y << 7;
    const int n0 = blockIdx.x << 7;

    const int srow = lane >> 3;
    const int clds = lane & 7;
    const int cg   = clds ^ srow;
    const ushort_t* pA = A + (size_t)(m0 + w * 32 + srow) * K + cg * 8;
    const ushort_t* pB = W + (size_t)(n0 + w * 32 + srow) * K + cg * 8;
    ushort_t* lA = As + (w * 32) * 64;
    ushort_t* lB = Bs + (w * 32) * 64;

    f32x4 acc[4][4];
#pragma unroll
    for (int mi = 0; mi < 4; ++mi)
#pragma unroll
        for (int ni = 0; ni < 4; ++ni) acc[mi][ni] = (f32x4){0.f, 0.f, 0.f, 0.f};

    const int s7  = l16 & 7;
    const int ck0 = (lg ^ s7) << 3;
    const int ck1 = ((4 | lg) ^ s7) << 3;
    const int arow = (wm * 64 + l16) * 64;
    const int brow = (wn * 64 + l16) * 64;

    const int KT = K >> 6;
    for (int kt = 0; kt < KT; ++kt) {
        __syncthreads();
        const ushort_t* ga = pA + kt * 64;
        const ushort_t* gb = pB + kt * 64;
#pragma unroll
        for (int j = 0; j < 4; ++j) {
            gload_lds16(ga + (size_t)j * 8 * K, lA + j * 8 * 64);
            gload_lds16(gb + (size_t)j * 8 * K, lB + j * 8 * 64);
        }
        __syncthreads();

        bf16x8 af[2][4], bfr[2][4];
#pragma unroll
        for (int mi = 0; mi < 4; ++mi) {
            af[0][mi] = *(const bf16x8*)(As + arow + mi * 16 * 64 + ck0);
            af[1][mi] = *(const bf16x8*)(As + arow + mi * 16 * 64 + ck1);
        }
#pragma unroll
        for (int ni = 0; ni < 4; ++ni) {
            bfr[0][ni] = *(const bf16x8*)(Bs + brow + ni * 16 * 64 + ck0);
            bfr[1][ni] = *(const bf16x8*)(Bs + brow + ni * 16 * 64 + ck1);
        }
#pragma unroll
        for (int kk = 0; kk < 2; ++kk)
#pragma unroll
            for (int mi = 0; mi < 4; ++mi)
#pragma unroll
                for (int ni = 0; ni < 4; ++ni)
                    acc[mi][ni] = __builtin_amdgcn_mfma_f32_16x16x32_bf16(
                        af[kk][mi], bfr[kk][ni], acc[mi][ni], 0, 0, 0);
    }

#pragma unroll
    for (int ni = 0; ni < 4; ++ni) {
        const int n = n0 + wn * 64 + ni * 16 + l16;
        const float bv = bias[n];
        if (MODE == 0) {
            float* out = (float*)outp;
#pragma unroll
            for (int mi = 0; mi < 4; ++mi)
#pragma unroll
                for (int r = 0; r < 4; ++r) {
                    const int m = m0 + wm * 64 + mi * 16 + lg * 4 + r;
                    out[(size_t)m * N + n] = acc[mi][ni][r] + bv;
                }
        } else {
            ushort_t* out = (ushort_t*)outp;
            const int which = n / DIM;       // 0=q 1=k 2=v
            const int rem   = n % DIM;
            const int h = rem >> 6;
            const int d = rem & 63;
            if (which < 2) {
                const float sc = (which == 0) ? QSCALE : 1.0f;
                ushort_t* base = out + (size_t)which * QKVSZ;
#pragma unroll
                for (int mi = 0; mi < 4; ++mi)
#pragma unroll
                    for (int r = 0; r < 4; ++r) {
                        const int m = m0 + wm * 64 + mi * 16 + lg * 4 + r;
                        const int b = m >> 11;
                        const int nrow = m & (SEQ - 1);
                        base[((size_t)(b * HEADS + h) * SEQ + nrow) * HDIM + d] =
                            f2bf((acc[mi][ni][r] + bv) * sc);
                    }
            } else {
                // V^T [bh][d][SEQ], packed 4-wide along seq
                ushort_t* base = out + 2 * QKVSZ;
#pragma unroll
                for (int mi = 0; mi < 4; ++mi) {
                    const int m = m0 + wm * 64 + mi * 16 + lg * 4;
                    const int b = m >> 11;
                    const int nrow = m & (SEQ - 1);
                    ushort4 pk;
                    pk.x = f2bf(acc[mi][ni][0] + bv);
                    pk.y = f2bf(acc[mi][ni][1] + bv);
                    pk.z = f2bf(acc[mi][ni][2] + bv);
                    pk.w = f2bf(acc[mi][ni][3] + bv);
                    *(ushort4*)&base[((size_t)(b * HEADS + h) * HDIM + d) * SEQ + nrow] = pk;
                }
            }
        }
    }
}

// ---------------------------------------------------------------------------
// 8-wave kv-parity-split flash attention. 512 thr = 2 groups x 4 waves.
// Group g handles kv tiles kt = 2i+g (KVB=32); each pair (w, w+4) owns the
// same 32 q-rows; fixed-max softmax => partials additive; pair-combine via
// LDS at the end. Group-private double-buffered K/V^T staging (gload_lds,
// pre-swizzled global source).
// ---------------------------------------------------------------------------
__global__ __launch_bounds__(512) void flash_attn_mfma(
    const ushort_t* __restrict__ Qg, const ushort_t* __restrict__ Kg,
    const ushort_t* __restrict__ VTg, ushort_t* __restrict__ Og)
{
    __shared__ __align__(16) unsigned char smem[33792];
    // KV: buffer(grp,par,which) = (ushort*)smem + ((grp*2+par)*2+which)*2048
    // after loop, aliased: exO = (float*)smem [pair][2048], exL at +32768

    const int tid  = threadIdx.x;
    const int lane = tid & 63;
    const int w    = tid >> 6;       // 0..7
    const int wi   = w & 3;
    const int grp  = w >> 2;
    const int l32  = lane & 31;
    const int hi   = lane >> 5;

    // bijective XCD swizzle: 768 = 8 x 96
    const int L   = blockIdx.x;
    const int swz = (L & 7) * 96 + (L >> 3);
    const int bh  = swz >> 4;
    const int qt  = swz & 15;
    const int q0  = qt * 128 + wi * 32;

    const ushort_t* Qp  = Qg + ((size_t)bh * SEQ + q0) * HDIM;
    const ushort_t* Kp  = Kg + (size_t)bh * SEQ * HDIM;
    const ushort_t* VTp = VTg + (size_t)bh * HDIM * SEQ;

    ushort_t* kv = (ushort_t*)smem;

    // Q B-frags: lane q=l32, d = kd*16 + hi*8 + j
    bf16x8 qf[4];
#pragma unroll
    for (int kd = 0; kd < 4; ++kd)
        qf[kd] = *(const bf16x8*)(Qp + l32 * HDIM + kd * 16 + hi * 8);

    f32x16 oacc[2];
#pragma unroll
    for (int nb = 0; nb < 2; ++nb)
#pragma unroll
        for (int r = 0; r < 16; ++r) oacc[nb][r] = 0.f;
    float lsum = 0.f;

    // staging lane geometry (LDS dest = uniform base + lane*16B)
    const int krow = wi * 8 + (lane >> 3);           // K tile row
    const int kcg  = (lane & 7) ^ (lane >> 3);       // pre-swizzled K chunk
    const int vd   = wi * 16 + (lane >> 2);          // V^T d-row
    const int vcg  = (lane & 3) ^ ((vd >> 1) & 3);   // pre-swizzled V chunk

    auto stage = [&](int par, int kt) {
        ushort_t* lk = kv + ((grp * 2 + par) * 2 + 0) * 2048 + wi * 512;
        ushort_t* lv = kv + ((grp * 2 + par) * 2 + 1) * 2048 + wi * 512;
        gload_lds16(Kp + ((size_t)kt * KVB + krow) * HDIM + kcg * 8, lk);
        gload_lds16(VTp + (size_t)vd * SEQ + kt * KVB + vcg * 8, lv);
    };

    stage(0, grp);
    __syncthreads();

    const int NI = SEQ / KVB / 2;   // 32 rounds per group
    for (int i = 0; i < NI; ++i) {
        if (i + 1 < NI) stage((i + 1) & 1, 2 * (i + 1) + grp);

        const ushort_t* Kb = kv + ((grp * 2 + (i & 1)) * 2 + 0) * 2048;
        const ushort_t* Vb = kv + ((grp * 2 + (i & 1)) * 2 + 1) * 2048;

        // ---- S^T: A = K rows (m=kv), B = Q (n=q) ----
        f32x16 sacc;
#pragma unroll
        for (int r = 0; r < 16; ++r) sacc[r] = 0.f;
        const int s7 = l32 & 7;
        __builtin_amdgcn_s_setprio(1);
#pragma unroll
        for (int kd = 0; kd < 4; ++kd) {
            bf16x8 kf = *(const bf16x8*)(Kb + l32 * 64 + (((kd * 2 + hi) ^ s7) << 3));
            sacc = __builtin_amdgcn_mfma_f32_32x32x16_bf16(kf, qf[kd], sacc, 0, 0, 0);
        }
        __builtin_amdgcn_s_setprio(0);

        // ---- fixed-max softmax ----
        float p[16];
#pragma unroll
        for (int r = 0; r < 16; ++r) p[r] = exp2f(sacc[r] - MFIX);
        float t0 = (p[0] + p[1]) + (p[2] + p[3]);
        float t1 = (p[4] + p[5]) + (p[6] + p[7]);
        float t2 = (p[8] + p[9]) + (p[10] + p[11]);
        float t3 = (p[12] + p[13]) + (p[14] + p[15]);
        lsum += (t0 + t1) + (t2 + t3);

        // ---- PV ----
#pragma unroll
        for (int s = 0; s < 2; ++s) {
            unsigned int x0 = cvtpk(p[8 * s + 0], p[8 * s + 1]);
            unsigned int y0 = cvtpk(p[8 * s + 4], p[8 * s + 5]);
            unsigned int x1 = cvtpk(p[8 * s + 2], p[8 * s + 3]);
            unsigned int y1 = cvtpk(p[8 * s + 6], p[8 * s + 7]);
            asm("v_permlane32_swap_b32 %0, %1" : "+v"(x0), "+v"(y0));
            asm("v_permlane32_swap_b32 %0, %1" : "+v"(x1), "+v"(y1));
            union { bf16x8 v; unsigned int w4[4]; } pa;
            pa.w4[0] = x0; pa.w4[1] = x1; pa.w4[2] = y0; pa.w4[3] = y1;
            const int kc = s * 2 + hi;
            __builtin_amdgcn_s_setprio(1);
#pragma unroll
            for (int nb = 0; nb < 2; ++nb) {
                int d = nb * 32 + l32;
                bf16x8 vf = *(const bf16x8*)(Vb + d * 32 + ((kc ^ ((d >> 1) & 3)) << 3));
                oacc[nb] = __builtin_amdgcn_mfma_f32_32x32x16_bf16(
                    pa.v, vf, oacc[nb], 0, 0, 0);
            }
            __builtin_amdgcn_s_setprio(0);
        }

        __syncthreads();
    }

    // ---- pair combine + epilogue ----
    lsum += __shfl_xor(lsum, 32);
    __syncthreads();                      // loop LDS quiesced; safe to alias
    float* exO = (float*)smem;            // [pair][2048]
    float* exL = (float*)(smem + 32768);  // [pair][64]
    if (grp == 1) {
#pragma unroll
        for (int nb = 0; nb < 2; ++nb)
#pragma unroll
            for (int r = 0; r < 16; ++r)
                exO[wi * 2048 + (nb * 16 + r) * 64 + lane] = oacc[nb][r];
        exL[wi * 64 + lane] = lsum;
    }
    __syncthreads();
    if (grp == 0) {
        lsum += exL[wi * 64 + lane];
#pragma unroll
        for (int nb = 0; nb < 2; ++nb)
#pragma unroll
            for (int r = 0; r < 16; ++r)
                oacc[nb][r] += exO[wi * 2048 + (nb * 16 + r) * 64 + lane];
        float linv = 1.0f / lsum;
        const int b_ = bh / HEADS;
        const int h_ = bh % HEADS;
        ushort_t* Ob = Og + ((size_t)b_ * SEQ + q0) * DIM + h_ * HDIM;
#pragma unroll
        for (int r = 0; r < 16; ++r) {
            int q = (r & 3) + 8 * (r >> 2) + 4 * hi;
            float li = __shfl(linv, q);
#pragma unroll
            for (int nb = 0; nb < 2; ++nb)
                Ob[(size_t)q * DIM + nb * 32 + l32] = f2bf(oacc[nb][r] * li);
        }
    }
}

// ---------------------------------------------------------------------------
extern "C" void kernel_launch(void* const* d_in, const int* in_sizes, int n_in,
                              void* d_out, int out_size, void* d_ws, size_t ws_size,
                              hipStream_t stream)
{
    const float* x      = (const float*)d_in[0];
    const float* qkv_w  = (const float*)d_in[1];
    const float* qkv_b  = (const float*)d_in[2];
    const float* proj_w = (const float*)d_in[3];
    const float* proj_b = (const float*)d_in[4];
    float* out = (float*)d_out;

    ushort_t* qb     = (ushort_t*)d_ws;           // Q [bh][SEQ][64]
    ushort_t* kb     = qb + QKVSZ;                // K [bh][SEQ][64]
    ushort_t* vtb    = qb + 2 * QKVSZ;            // V^T [bh][64][SEQ]
    ushort_t* attn   = qb + 3 * QKVSZ;            // [M][768] bf16
    ushort_t* xb     = qb + 4 * QKVSZ;            // [M][768] bf16
    ushort_t* qkvwb  = xb + QKVSZ;
    ushort_t* projwb = qkvwb + (size_t)3 * DIM * DIM;

    const int M = BATCH * SEQ;
    const int NX  = M * DIM;
    const int NQW = 3 * DIM * DIM;
    const int NPW = DIM * DIM;

    cvt3<<<dim3((NX + NQW + NPW) / (8 * 256)), dim3(256), 0, stream>>>(
        x, xb, NX / 8, qkv_w, qkvwb, NQW / 8, proj_w, projwb, NPW / 8);

    dim3 g1(3 * DIM / 128, M / 128);
    gemm_mfma<1><<<g1, dim3(256), 0, stream>>>(xb, qkvwb, qkv_b, (void*)qb, M, 3 * DIM, DIM);

    flash_attn_mfma<<<dim3(768), dim3(512), 0, stream>>>(qb, kb, vtb, attn);

    dim3 g3(DIM / 128, M / 128);
    gemm_mfma<0><<<g3, dim3(256), 0, stream>>>(attn, projwb, proj_b, (void*)out, M, DIM, DIM);
}

// Round 7
// 146.317 us; speedup vs baseline: 1.0955x; 1.0955x over previous
//
#include <hip/hip_runtime.h>

#define DIM 768
#define HEADS 12
#define HDIM 64
#define BATCH 4
#define SEQ 2048
#define QSCALE 0.1803368787f   // 0.125 * log2(e) -> softmax in exp2 domain
#define MFIX 16.0f             // fixed softmax max bound (exp2 domain)
#define QKVSZ ((size_t)BATCH * HEADS * SEQ * HDIM)

typedef __bf16 bf16x8 __attribute__((ext_vector_type(8)));
typedef float  f32x4  __attribute__((ext_vector_type(4)));
typedef float  f32x16 __attribute__((ext_vector_type(16)));
typedef unsigned short u16x8 __attribute__((ext_vector_type(8)));
typedef unsigned short ushort_t;

__device__ inline float exp2_hw(float x){
    float r;
    asm("v_exp_f32 %0, %1\n\ts_nop 0" : "=v"(r) : "v"(x));
    return r;
}
__device__ inline unsigned short f2bf(float x){
    unsigned int u = __float_as_uint(x);
    u += 0x7fffu + ((u >> 16) & 1u);
    return (unsigned short)(u >> 16);
}
__device__ inline unsigned int cvtpk(float lo, float hi){
    unsigned int r;
    asm("v_cvt_pk_bf16_f32 %0, %1, %2" : "=v"(r) : "v"(lo), "v"(hi));
    return r;
}
__device__ inline void gload_lds16(const void* g, void* lds) {
    __builtin_amdgcn_global_load_lds(
        (const __attribute__((address_space(1))) void*)g,
        (__attribute__((address_space(3))) void*)lds, 16, 0, 0);
}

// ---------------------------------------------------------------------------
// fp32 -> bf16 conversion for x, qkv_w, proj_w (8 elems/thread)
// ---------------------------------------------------------------------------
__global__ __launch_bounds__(256) void cvt3(
    const float* __restrict__ s0, ushort_t* __restrict__ d0, int v0,
    const float* __restrict__ s1, ushort_t* __restrict__ d1, int v1,
    const float* __restrict__ s2, ushort_t* __restrict__ d2, int v2)
{
    int idx = blockIdx.x * 256 + threadIdx.x;
    const float* s; ushort_t* d;
    if (idx < v0)           { s = s0; d = d0; }
    else if (idx < v0 + v1) { idx -= v0; s = s1; d = d1; }
    else                    { idx -= v0 + v1; s = s2; d = d2; }
    float4 a = *(const float4*)(s + (size_t)idx * 8);
    float4 b = *(const float4*)(s + (size_t)idx * 8 + 4);
    u16x8 p;
    p[0] = f2bf(a.x); p[1] = f2bf(a.y); p[2] = f2bf(a.z); p[3] = f2bf(a.w);
    p[4] = f2bf(b.x); p[5] = f2bf(b.y); p[6] = f2bf(b.z); p[7] = f2bf(b.w);
    *(u16x8*)(d + (size_t)idx * 8) = p;
}

// ---------------------------------------------------------------------------
// bf16 MFMA GEMM: C[M,N] = A[M,K] @ W[N,K]^T + bias[N]
// MODE 0: fp32 store. MODE 1: bf16 scatter -> Q[bh][n][d] (scaled), K[bh][n][d],
//         V^T[bh][d][SEQ] (packed ushort4 along seq).
// ---------------------------------------------------------------------------
template <int MODE>
__global__ __launch_bounds__(256) void gemm_mfma(
    const ushort_t* __restrict__ A, const ushort_t* __restrict__ W,
    const float* __restrict__ bias, void* __restrict__ outp,
    int M, int N, int K)
{
    __shared__ ushort_t As[128 * 64];
    __shared__ ushort_t Bs[128 * 64];

    const int tid  = threadIdx.x;
    const int lane = tid & 63;
    const int w    = tid >> 6;
    const int l16  = lane & 15;
    const int lg   = lane >> 4;
    const int wm = w >> 1, wn = w & 1;
    const int m0 = blockIdx.y << 7;
    const int n0 = blockIdx.x << 7;

    const int srow = lane >> 3;
    const int clds = lane & 7;
    const int cg   = clds ^ srow;
    const ushort_t* pA = A + (size_t)(m0 + w * 32 + srow) * K + cg * 8;
    const ushort_t* pB = W + (size_t)(n0 + w * 32 + srow) * K + cg * 8;
    ushort_t* lA = As + (w * 32) * 64;
    ushort_t* lB = Bs + (w * 32) * 64;

    f32x4 acc[4][4];
#pragma unroll
    for (int mi = 0; mi < 4; ++mi)
#pragma unroll
        for (int ni = 0; ni < 4; ++ni) acc[mi][ni] = (f32x4){0.f, 0.f, 0.f, 0.f};

    const int s7  = l16 & 7;
    const int ck0 = (lg ^ s7) << 3;
    const int ck1 = ((4 | lg) ^ s7) << 3;
    const int arow = (wm * 64 + l16) * 64;
    const int brow = (wn * 64 + l16) * 64;

    const int KT = K >> 6;
    for (int kt = 0; kt < KT; ++kt) {
        __syncthreads();
        const ushort_t* ga = pA + kt * 64;
        const ushort_t* gb = pB + kt * 64;
#pragma unroll
        for (int j = 0; j < 4; ++j) {
            gload_lds16(ga + (size_t)j * 8 * K, lA + j * 8 * 64);
            gload_lds16(gb + (size_t)j * 8 * K, lB + j * 8 * 64);
        }
        __syncthreads();

        bf16x8 af[2][4], bfr[2][4];
#pragma unroll
        for (int mi = 0; mi < 4; ++mi) {
            af[0][mi] = *(const bf16x8*)(As + arow + mi * 16 * 64 + ck0);
            af[1][mi] = *(const bf16x8*)(As + arow + mi * 16 * 64 + ck1);
        }
#pragma unroll
        for (int ni = 0; ni < 4; ++ni) {
            bfr[0][ni] = *(const bf16x8*)(Bs + brow + ni * 16 * 64 + ck0);
            bfr[1][ni] = *(const bf16x8*)(Bs + brow + ni * 16 * 64 + ck1);
        }
#pragma unroll
        for (int kk = 0; kk < 2; ++kk)
#pragma unroll
            for (int mi = 0; mi < 4; ++mi)
#pragma unroll
                for (int ni = 0; ni < 4; ++ni)
                    acc[mi][ni] = __builtin_amdgcn_mfma_f32_16x16x32_bf16(
                        af[kk][mi], bfr[kk][ni], acc[mi][ni], 0, 0, 0);
    }

#pragma unroll
    for (int ni = 0; ni < 4; ++ni) {
        const int n = n0 + wn * 64 + ni * 16 + l16;
        const float bv = bias[n];
        if (MODE == 0) {
            float* out = (float*)outp;
#pragma unroll
            for (int mi = 0; mi < 4; ++mi)
#pragma unroll
                for (int r = 0; r < 4; ++r) {
                    const int m = m0 + wm * 64 + mi * 16 + lg * 4 + r;
                    out[(size_t)m * N + n] = acc[mi][ni][r] + bv;
                }
        } else {
            ushort_t* out = (ushort_t*)outp;
            const int which = n / DIM;       // 0=q 1=k 2=v
            const int rem   = n % DIM;
            const int h = rem >> 6;
            const int d = rem & 63;
            if (which < 2) {
                const float sc = (which == 0) ? QSCALE : 1.0f;
                ushort_t* base = out + (size_t)which * QKVSZ;
#pragma unroll
                for (int mi = 0; mi < 4; ++mi)
#pragma unroll
                    for (int r = 0; r < 4; ++r) {
                        const int m = m0 + wm * 64 + mi * 16 + lg * 4 + r;
                        const int b = m >> 11;
                        const int nrow = m & (SEQ - 1);
                        base[((size_t)(b * HEADS + h) * SEQ + nrow) * HDIM + d] =
                            f2bf((acc[mi][ni][r] + bv) * sc);
                    }
            } else {
                // V^T [bh][d][SEQ], packed 4-wide along seq
                ushort_t* base = out + 2 * QKVSZ;
#pragma unroll
                for (int mi = 0; mi < 4; ++mi) {
                    const int m = m0 + wm * 64 + mi * 16 + lg * 4;
                    const int b = m >> 11;
                    const int nrow = m & (SEQ - 1);
                    ushort4 pk;
                    pk.x = f2bf(acc[mi][ni][0] + bv);
                    pk.y = f2bf(acc[mi][ni][1] + bv);
                    pk.z = f2bf(acc[mi][ni][2] + bv);
                    pk.w = f2bf(acc[mi][ni][3] + bv);
                    *(ushort4*)&base[((size_t)(b * HEADS + h) * HDIM + d) * SEQ + nrow] = pk;
                }
            }
        }
    }
}

// ---------------------------------------------------------------------------
// Swapped-QK^T 32x32 MFMA flash attention, fixed-max softmax.
// 4 waves x 32 q-rows; KV tile 64, double-buffered gload_lds staging.
// VALU-trimmed: sacc C-init = -MFIX (no subs); row-sums l via ones-MFMA
// (no adds, no shfl reduce); pointer-incremented staging.
// ---------------------------------------------------------------------------
__global__ __launch_bounds__(256) void flash_attn_mfma(
    const ushort_t* __restrict__ Qg, const ushort_t* __restrict__ Kg,
    const ushort_t* __restrict__ VTg, ushort_t* __restrict__ Og)
{
    __shared__ ushort_t Ks[2][4096];   // [kv][d], chunk ^= kv&7
    __shared__ ushort_t Vs[2][4096];   // V^T [d][kv], chunk ^= d&7

    const int tid  = threadIdx.x;
    const int lane = tid & 63;
    const int w    = tid >> 6;
    const int l32  = lane & 31;
    const int hi   = lane >> 5;

    // bijective XCD swizzle: 768 = 8 x 96
    const int L   = blockIdx.x;
    const int swz = (L & 7) * 96 + (L >> 3);
    const int bh  = swz >> 4;
    const int qt  = swz & 15;
    const int q0  = qt * 128 + w * 32;

    const ushort_t* Qp  = Qg + ((size_t)bh * SEQ + q0) * HDIM;
    const ushort_t* Kp  = Kg + (size_t)bh * SEQ * HDIM;
    const ushort_t* VTp = VTg + (size_t)bh * HDIM * SEQ;

    // Q B-frags: lane q=l32, d = kd*16 + hi*8 + j
    bf16x8 qf[4];
#pragma unroll
    for (int kd = 0; kd < 4; ++kd)
        qf[kd] = *(const bf16x8*)(Qp + l32 * HDIM + kd * 16 + hi * 8);

    // ones B-frag for row-sum MFMA
    bf16x8 ones;
    {
        union { bf16x8 v; unsigned int w4[4]; } u;
        u.w4[0] = u.w4[1] = u.w4[2] = u.w4[3] = 0x3F803F80u;
        ones = u.v;
    }

    f32x16 oacc[2], lacc;
#pragma unroll
    for (int nb = 0; nb < 2; ++nb)
#pragma unroll
        for (int r = 0; r < 16; ++r) oacc[nb][r] = 0.f;
#pragma unroll
    for (int r = 0; r < 16; ++r) lacc[r] = 0.f;

    // staging lane geometry: wave w covers rows w*16 + srow (+8), swizzled chunk
    const int srow = lane >> 3;
    const int clds = lane & 7;
    const int cg   = clds ^ srow;
    const int rw   = w * 16 + srow;

    const ushort_t* gk = Kp + (size_t)rw * HDIM + cg * 8;
    const ushort_t* gv = VTp + (size_t)rw * SEQ + cg * 8;
    ushort_t* lk0 = &Ks[0][0] + w * 1024;
    ushort_t* lv0 = &Vs[0][0] + w * 1024;

    auto stage = [&](int buf) {
        ushort_t* lkb = lk0 + (buf << 12);
        ushort_t* lvb = lv0 + (buf << 12);
        gload_lds16(gk, lkb);
        gload_lds16(gk + 8 * HDIM, lkb + 512);
        gload_lds16(gv, lvb);
        gload_lds16(gv + 8 * SEQ, lvb + 512);
    };

    stage(0);
    gk += 64 * HDIM; gv += 64;
    __syncthreads();

    int cur = 0;
    const int NT = SEQ / 64;
    for (int kt = 0; kt < NT; ++kt) {
        if (kt + 1 < NT) {
            stage(cur ^ 1);
            gk += 64 * HDIM; gv += 64;
        }

        const ushort_t* Kb = &Ks[0][0] + (cur << 12);
        const ushort_t* Vb = &Vs[0][0] + (cur << 12);

#pragma unroll
        for (int b = 0; b < 2; ++b) {
            // ---- S^T block: A = K rows (m=kv), B = Q (n=q); C-init = -MFIX ----
            f32x16 sacc;
#pragma unroll
            for (int r = 0; r < 16; ++r) sacc[r] = -MFIX;
            const int arow = b * 32 + l32;
            const int s7   = l32 & 7;
            __builtin_amdgcn_s_setprio(1);
#pragma unroll
            for (int kd = 0; kd < 4; ++kd) {
                bf16x8 kf = *(const bf16x8*)(Kb + arow * 64 + (((kd * 2 + hi) ^ s7) << 3));
                sacc = __builtin_amdgcn_mfma_f32_32x32x16_bf16(kf, qf[kd], sacc, 0, 0, 0);
            }
            __builtin_amdgcn_s_setprio(0);

            // ---- p = exp2(s) (MFIX pre-folded), lane-local ----
            float p[16];
#pragma unroll
            for (int r = 0; r < 16; ++r) p[r] = exp2_hw(sacc[r]);

            // ---- rebuild PV A-frags; l and O both via MFMA ----
#pragma unroll
            for (int s = 0; s < 2; ++s) {
                unsigned int x0 = cvtpk(p[8 * s + 0], p[8 * s + 1]);
                unsigned int y0 = cvtpk(p[8 * s + 4], p[8 * s + 5]);
                unsigned int x1 = cvtpk(p[8 * s + 2], p[8 * s + 3]);
                unsigned int y1 = cvtpk(p[8 * s + 6], p[8 * s + 7]);
                asm("v_permlane32_swap_b32 %0, %1" : "+v"(x0), "+v"(y0));
                asm("v_permlane32_swap_b32 %0, %1" : "+v"(x1), "+v"(y1));
                union { bf16x8 v; unsigned int w4[4]; } pa;
                pa.w4[0] = x0; pa.w4[1] = x1; pa.w4[2] = y0; pa.w4[3] = y1;
                const int kc = b * 4 + s * 2 + hi;
                __builtin_amdgcn_s_setprio(1);
                lacc = __builtin_amdgcn_mfma_f32_32x32x16_bf16(pa.v, ones, lacc, 0, 0, 0);
#pragma unroll
                for (int nb = 0; nb < 2; ++nb) {
                    int d = nb * 32 + l32;
                    bf16x8 vf = *(const bf16x8*)(Vb + d * 64 + ((kc ^ (d & 7)) << 3));
                    oacc[nb] = __builtin_amdgcn_mfma_f32_32x32x16_bf16(
                        pa.v, vf, oacc[nb], 0, 0, 0);
                }
                __builtin_amdgcn_s_setprio(0);
            }
        }

        __syncthreads();   // next buffer staged; all reads of cur done
        cur ^= 1;
    }

    // ---- epilogue: lacc[r] holds l for q=crow(r,hi) on every lane ----
    const int b_ = bh / HEADS;
    const int h_ = bh % HEADS;
    ushort_t* Ob = Og + ((size_t)b_ * SEQ + q0) * DIM + h_ * HDIM;
#pragma unroll
    for (int r = 0; r < 16; ++r) {
        int q = (r & 3) + 8 * (r >> 2) + 4 * hi;
        float li = __builtin_amdgcn_rcpf(lacc[r]);
#pragma unroll
        for (int nb = 0; nb < 2; ++nb)
            Ob[(size_t)q * DIM + nb * 32 + l32] = f2bf(oacc[nb][r] * li);
    }
}

// ---------------------------------------------------------------------------
extern "C" void kernel_launch(void* const* d_in, const int* in_sizes, int n_in,
                              void* d_out, int out_size, void* d_ws, size_t ws_size,
                              hipStream_t stream)
{
    const float* x      = (const float*)d_in[0];
    const float* qkv_w  = (const float*)d_in[1];
    const float* qkv_b  = (const float*)d_in[2];
    const float* proj_w = (const float*)d_in[3];
    const float* proj_b = (const float*)d_in[4];
    float* out = (float*)d_out;

    ushort_t* qb     = (ushort_t*)d_ws;           // Q [bh][SEQ][64]
    ushort_t* kb     = qb + QKVSZ;                // K [bh][SEQ][64]
    ushort_t* vtb    = qb + 2 * QKVSZ;            // V^T [bh][64][SEQ]
    ushort_t* attn   = qb + 3 * QKVSZ;            // [M][768] bf16
    ushort_t* xb     = qb + 4 * QKVSZ;            // [M][768] bf16
    ushort_t* qkvwb  = xb + QKVSZ;
    ushort_t* projwb = qkvwb + (size_t)3 * DIM * DIM;

    const int M = BATCH * SEQ;
    const int NX  = M * DIM;
    const int NQW = 3 * DIM * DIM;
    const int NPW = DIM * DIM;

    cvt3<<<dim3((NX + NQW + NPW) / (8 * 256)), dim3(256), 0, stream>>>(
        x, xb, NX / 8, qkv_w, qkvwb, NQW / 8, proj_w, projwb, NPW / 8);

    dim3 g1(3 * DIM / 128, M / 128);
    gemm_mfma<1><<<g1, dim3(256), 0, stream>>>(xb, qkvwb, qkv_b, (void*)qb, M, 3 * DIM, DIM);

    flash_attn_mfma<<<dim3(768), dim3(256), 0, stream>>>(qb, kb, vtb, attn);

    dim3 g3(DIM / 128, M / 128);
    gemm_mfma<0><<<g3, dim3(256), 0, stream>>>(attn, projwb, proj_b, (void*)out, M, DIM, DIM);
}